// Round 5
// baseline (419.420 us; speedup 1.0000x reference)
//
#include <hip/hip_runtime.h>
#include <hip/hip_bf16.h>
#include <cstdint>
#include <cstddef>

// Problem dims (fixed)
#define BB 16
#define LL 2048
#define MM (BB * LL)   // 32768 rows
#define KK 1024        // inner dim
#define HH 1024        // hidden per gate

typedef __attribute__((ext_vector_type(8))) short bf16x8;
typedef __attribute__((ext_vector_type(4))) float f32x4;

// ---------- fp32 -> bf16 (RNE) ----------
__device__ __forceinline__ unsigned short f2bf(float f) {
    unsigned u = __builtin_bit_cast(unsigned, f);
    u += 0x7fffu + ((u >> 16) & 1u);
    return (unsigned short)(u >> 16);
}

__global__ void cvt_f32_to_bf16(const float* __restrict__ in,
                                unsigned short* __restrict__ out, int n8) {
    int i = blockIdx.x * blockDim.x + threadIdx.x;
    if (i >= n8) return;
    const float4* p = reinterpret_cast<const float4*>(in) + (size_t)i * 2;
    float4 v0 = p[0];
    float4 v1 = p[1];
    union { unsigned short us[8]; uint4 v; } o;
    o.us[0] = f2bf(v0.x); o.us[1] = f2bf(v0.y);
    o.us[2] = f2bf(v0.z); o.us[3] = f2bf(v0.w);
    o.us[4] = f2bf(v1.x); o.us[5] = f2bf(v1.y);
    o.us[6] = f2bf(v1.z); o.us[7] = f2bf(v1.w);
    reinterpret_cast<uint4*>(out)[i] = o.v;
}

// ---------- mask scan ----------
__global__ __launch_bounds__(1024) void scan_mask(const int* __restrict__ mask,
                                                  int* __restrict__ rows,
                                                  int* __restrict__ Na) {
    __shared__ int psum[1024];
    const int t = threadIdx.x;
    const int base = t * 32;
    int m[32];
    int cnt = 0;
#pragma unroll
    for (int i = 0; i < 32; ++i) { m[i] = mask[base + i]; cnt += (m[i] != 0); }
    psum[t] = cnt;
    __syncthreads();
    for (int off = 1; off < 1024; off <<= 1) {
        int v = (t >= off) ? psum[t - off] : 0;
        __syncthreads();
        psum[t] += v;
        __syncthreads();
    }
    int offset = psum[t] - cnt;
#pragma unroll
    for (int i = 0; i < 32; ++i) {
        if (m[i]) rows[offset++] = base + i;
    }
    if (t == 1023) *Na = psum[1023];
}

// ---------- gather active rows of x, f32 -> bf16 ----------
__global__ __launch_bounds__(256) void gather_cvt(const float* __restrict__ x,
                                                  const int* __restrict__ rows,
                                                  const int* __restrict__ Na,
                                                  unsigned short* __restrict__ xbf) {
    const int j = blockIdx.x;
    if (j >= *Na) return;
    const int r = rows[j];
    const float4 v = reinterpret_cast<const float4*>(x + (size_t)r * KK)[threadIdx.x];
    ushort4 o;
    o.x = f2bf(v.x); o.y = f2bf(v.y); o.z = f2bf(v.z); o.w = f2bf(v.w);
    reinterpret_cast<ushort4*>(xbf + (size_t)j * KK)[threadIdx.x] = o;
}

// ---------- exact zeros for masked-out output rows ----------
__global__ __launch_bounds__(256) void zero_masked(const int* __restrict__ mask,
                                                   float* __restrict__ out) {
    const int m = blockIdx.x;
    if (mask[m] != 0) return;
    const int bb = m >> 11;
    const int ll = m & 2047;
    float4 z = {0.f, 0.f, 0.f, 0.f};
    reinterpret_cast<float4*>(out + ((size_t)ll * BB + bb) * HH)[threadIdx.x] = z;
}

// ---------- async global->LDS, 16B per lane ----------
__device__ __forceinline__ void gload16(const unsigned short* g, unsigned short* l) {
    __builtin_amdgcn_global_load_lds(
        (const __attribute__((address_space(1))) unsigned int*)g,
        (__attribute__((address_space(3))) unsigned int*)l,
        16, 0, 0);
}

#define WAITVM2 asm volatile("s_waitcnt vmcnt(2)" ::: "memory")
#define WAITVM0 asm volatile("s_waitcnt vmcnt(0)" ::: "memory")
#define WAITLG0 asm volatile("s_waitcnt lgkmcnt(0)" ::: "memory")
#define SB      __builtin_amdgcn_sched_barrier(0)
#define BAR     __builtin_amdgcn_s_barrier()

// ---------- fused GEMM + GRU gating, 4-phase counted-vmcnt schedule ----------
// BM=256 rows, 64-col panel x 3 gates, BK=64, 8 waves (2M x 4N).
// LDS/buffer: A units A0..A3 (64 rows x 64k each) + B gates B0..B2 = 28672 sh.
// Swizzle: (row,k) at row*64 + (k ^ ((row&7)<<3)); staged via linear gload dest
// + inverse-swizzled global source column (rule #21; addressing verified r3).
//
// PHASE->UNIT MAP (the r4 bug): ph0/ph2 compute m-half 0 = rows wr*128+0..63
//   -> wr=0 reads unit A0, wr=1 reads unit A2.  ph1/ph3 (m-half 1) read A1/A3.
// So ph0 needs {A0,A2,B0,B1,B2}; ph1 needs {A1,A3}.
// Issue order everywhere: A0,A2 | B0,B1,B2 | A1,A3.
// Ledger (per-wave outstanding): loop-top {A1,A3}.
//   ph0: +stage{A0',A2'} (4) ... vmcnt(2) -> A1,A3 landed, leaves {A0',A2'}
//   ph1: +stage{B0',B1',B2'} (5)
//   ph2: +stage{A1',A3'} (7)
//   ph3: vmcnt(2) -> {A0',A2',B'} landed = ph0(kt+1) needs, leaves {A1',A3'}
// Each vmcnt precedes a BAR so confirmation is collective. Drain only in peel.
template <int MODE>
__global__ __launch_bounds__(512, 2) void gru_layer(
    const unsigned short* __restrict__ A,
    const unsigned short* __restrict__ W,
    const float* __restrict__ b_ih,
    const float* __restrict__ b_hh,
    const int* __restrict__ rows,
    const int* __restrict__ Na_p,
    unsigned short* __restrict__ out_bf,
    float* __restrict__ out_f) {
    __shared__ unsigned short lds[2][28672];  // 114688 B

    const int Na = *Na_p;
    const int m0 = blockIdx.x * 256;
    if (m0 >= Na) return;
    const int n0 = blockIdx.y * 64;

    const int tid  = threadIdx.x;
    const int lane = tid & 63;
    const int wid  = tid >> 6;
    const int wr   = wid >> 2;   // 0..1 (128 rows each)
    const int wc   = wid & 3;    // 0..3 (16 cols each)

    // --- staging sources: thread t -> unit-linear LDS slot t*16B ---
    const int trow = tid >> 3;                          // 0..63 within unit
    const int tcol = ((tid & 7) ^ (trow & 7)) * 8;      // inverse-swizzled k (shorts)
    int r0 = m0 + trow;        if (r0 >= Na) r0 = Na - 1;
    int r1 = m0 + 64 + trow;   if (r1 >= Na) r1 = Na - 1;
    int r2 = m0 + 128 + trow;  if (r2 >= Na) r2 = Na - 1;
    int r3 = m0 + 192 + trow;  if (r3 >= Na) r3 = Na - 1;
    const unsigned short* a0 = A + (size_t)r0 * KK + tcol;
    const unsigned short* a1 = A + (size_t)r1 * KK + tcol;
    const unsigned short* a2 = A + (size_t)r2 * KK + tcol;
    const unsigned short* a3 = A + (size_t)r3 * KK + tcol;
    const unsigned short* b0 = W + (size_t)(0 * HH + n0 + trow) * KK + tcol;
    const unsigned short* b1 = W + (size_t)(1 * HH + n0 + trow) * KK + tcol;
    const unsigned short* b2 = W + (size_t)(2 * HH + n0 + trow) * KK + tcol;

#define ST(ptr, kt, c, unit) gload16((ptr) + (kt) * 64, &lds[(c)][(unit) * 4096 + wid * 512])

    // --- read offsets (swizzled) ---
    const int l15  = lane & 15;
    const int akp0 = (((lane >> 4) << 3)) ^ ((lane & 7) << 3);        // ksub 0
    const int akp1 = (32 + ((lane >> 4) << 3)) ^ ((lane & 7) << 3);   // ksub 1
    int aoff0[4], aoff1[4], boff[3];
#pragma unroll
    for (int mf = 0; mf < 4; ++mf) {
        aoff0[mf] = (wr * 128 + 0 * 64 + mf * 16 + l15) * 64;   // units A0 / A2
        aoff1[mf] = (wr * 128 + 1 * 64 + mf * 16 + l15) * 64;   // units A1 / A3
    }
#pragma unroll
    for (int g = 0; g < 3; ++g)
        boff[g] = 16384 + g * 4096 + (wc * 16 + l15) * 64;

    f32x4 acc0[4][3] = {};
    f32x4 acc1[4][3] = {};
    bf16x8 afrag[4];
    bf16x8 bfrag[3];

#define READ_B(Lp, akp) do {                                                    \
        _Pragma("unroll") for (int g = 0; g < 3; ++g)                           \
            bfrag[g] = *reinterpret_cast<const bf16x8*>(&(Lp)[boff[g] + (akp)]); \
    } while (0)
#define READ_A0(Lp, akp) do {                                                    \
        _Pragma("unroll") for (int mf = 0; mf < 4; ++mf)                         \
            afrag[mf] = *reinterpret_cast<const bf16x8*>(&(Lp)[aoff0[mf] + (akp)]); \
    } while (0)
#define READ_A1(Lp, akp) do {                                                    \
        _Pragma("unroll") for (int mf = 0; mf < 4; ++mf)                         \
            afrag[mf] = *reinterpret_cast<const bf16x8*>(&(Lp)[aoff1[mf] + (akp)]); \
    } while (0)
#define PHASE_MFMA(accN) do {                                                   \
        __builtin_amdgcn_s_setprio(1);                                          \
        _Pragma("unroll") for (int g = 0; g < 3; ++g)                           \
            _Pragma("unroll") for (int mf = 0; mf < 4; ++mf)                    \
                accN[mf][g] = __builtin_amdgcn_mfma_f32_16x16x32_bf16(          \
                    afrag[mf], bfrag[g], accN[mf][g], 0, 0, 0);                 \
        __builtin_amdgcn_s_setprio(0);                                          \
    } while (0)

    // prologue: stage tile 0, issue order A0,A2 | B0,B1,B2 | A1,A3; confirm first 5
    ST(a0, 0, 0, 0); ST(a2, 0, 0, 2);
    ST(b0, 0, 0, 4); ST(b1, 0, 0, 5); ST(b2, 0, 0, 6);
    ST(a1, 0, 0, 1); ST(a3, 0, 0, 3);
    WAITVM2; BAR;

    int cur = 0;
#pragma unroll 1
    for (int kt = 0; kt < 15; ++kt) {
        unsigned short* L = &lds[cur][0];
        const int nc = cur ^ 1;
        // ---- ph0: (mh0, ks0) — reads A0/A2,B; stages A0',A2' ----
        READ_A0(L, akp0); READ_B(L, akp0);
        ST(a0, kt + 1, nc, 0); ST(a2, kt + 1, nc, 2);
        BAR; WAITLG0; SB;
        PHASE_MFMA(acc0);
        WAITVM2;   // A1,A3 (tile kt) landed; leaves {A0',A2'}
        BAR;
        // ---- ph1: (mh1, ks0) — reads A1/A3; stages B' ----
        READ_A1(L, akp0);
        ST(b0, kt + 1, nc, 4); ST(b1, kt + 1, nc, 5); ST(b2, kt + 1, nc, 6);
        BAR; WAITLG0; SB;
        PHASE_MFMA(acc1);
        BAR;
        // ---- ph2: (mh0, ks1) — stages A1',A3' ----
        READ_A0(L, akp1); READ_B(L, akp1);
        ST(a1, kt + 1, nc, 1); ST(a3, kt + 1, nc, 3);
        BAR; WAITLG0; SB;
        PHASE_MFMA(acc0);
        BAR;
        // ---- ph3: (mh1, ks1) ----
        READ_A1(L, akp1);
        BAR; WAITLG0; SB;
        PHASE_MFMA(acc1);
        WAITVM2;   // {A0',A2',B0',B1',B2'} landed = ph0(kt+1) needs; leaves {A1',A3'}
        BAR;
        cur ^= 1;
    }
    {   // ---- peeled last tile (kt = 15): no staging ----
        unsigned short* L = &lds[cur][0];
        READ_A0(L, akp0); READ_B(L, akp0);
        BAR; WAITLG0; SB;
        PHASE_MFMA(acc0);
        WAITVM0;   // drain A1,A3
        BAR;
        READ_A1(L, akp0);
        BAR; WAITLG0; SB;
        PHASE_MFMA(acc1);
        BAR;
        READ_A0(L, akp1); READ_B(L, akp1);
        BAR; WAITLG0; SB;
        PHASE_MFMA(acc0);
        BAR;
        READ_A1(L, akp1);
        WAITLG0; SB;
        PHASE_MFMA(acc1);
    }

    // --- epilogue: gating; C/D layout col = lane&15, row = (lane>>4)*4 + j ---
    const int col = n0 + wc * 16 + l15;
    const float br_b = b_ih[col] + b_hh[col];
    const float bz_b = b_ih[HH + col] + b_hh[HH + col];
    const float bn_i = b_ih[2 * HH + col];
    const float bn_h = b_hh[2 * HH + col];

#define EPILOGUE(accN, mh) do {                                                  \
        _Pragma("unroll") for (int mf = 0; mf < 4; ++mf) {                       \
            _Pragma("unroll") for (int j = 0; j < 4; ++j) {                      \
                const int row = m0 + wr * 128 + (mh) * 64 + mf * 16 +            \
                                (lane >> 4) * 4 + j;                             \
                if (row < Na) {                                                  \
                    const float r = 1.f / (1.f + __expf(-(accN[mf][0][j] + br_b))); \
                    const float z = 1.f / (1.f + __expf(-(accN[mf][1][j] + bz_b))); \
                    const float n = tanhf(accN[mf][2][j] + bn_i + r * bn_h);     \
                    const float h = (1.f - z) * n;                               \
                    if (MODE == 0) {                                             \
                        out_bf[(size_t)row * HH + col] = f2bf(h);                \
                    } else {                                                     \
                        const int orig = rows[row];                              \
                        const int bb = orig >> 11;                               \
                        const int ll = orig & 2047;                              \
                        out_f[((size_t)ll * BB + bb) * HH + col] = h;            \
                    }                                                            \
                }                                                                \
            }                                                                    \
        }                                                                        \
    } while (0)

    EPILOGUE(acc0, 0);
    EPILOGUE(acc1, 1);
#undef ST
#undef READ_B
#undef READ_A0
#undef READ_A1
#undef PHASE_MFMA
#undef EPILOGUE
}

extern "C" void kernel_launch(void* const* d_in, const int* in_sizes, int n_in,
                              void* d_out, int out_size, void* d_ws, size_t ws_size,
                              hipStream_t stream) {
    const float* x   = (const float*)d_in[0];
    const int*   msk = (const int*)d_in[1];
    const float* W0  = (const float*)d_in[2];
    const float* bi0 = (const float*)d_in[4];
    const float* bh0 = (const float*)d_in[5];
    const float* W1  = (const float*)d_in[6];
    const float* bi1 = (const float*)d_in[8];
    const float* bh1 = (const float*)d_in[9];
    float* out = (float*)d_out;

    char* ws = (char*)d_ws;
    unsigned short* xbf  = (unsigned short*)ws;                  // 67,108,864 B (worst case)
    unsigned short* h1bf = (unsigned short*)(ws + 67108864);     // 67,108,864 B (worst case)
    unsigned short* w0bf = (unsigned short*)(ws + 134217728);    //  6,291,456 B
    unsigned short* w1bf = (unsigned short*)(ws + 140509184);    //  6,291,456 B
    int* rows = (int*)(ws + 146800640);                          //    131,072 B
    int* Na   = (int*)(ws + 146931712);                          //          4 B

    scan_mask<<<1, 1024, 0, stream>>>(msk, rows, Na);

    cvt_f32_to_bf16<<<1536, 256, 0, stream>>>(W0, w0bf, 3 * HH * KK / 8);
    cvt_f32_to_bf16<<<1536, 256, 0, stream>>>(W1, w1bf, 3 * HH * KK / 8);

    zero_masked<<<MM, 256, 0, stream>>>(msk, out);
    gather_cvt<<<MM, 256, 0, stream>>>(x, rows, Na, xbf);

    dim3 grid(MM / 256, HH / 64);  // (128, 16) worst case; blocks past Na exit
    gru_layer<0><<<grid, 512, 0, stream>>>(xbf, w0bf, bi0, bh0, rows, Na, h1bf, nullptr);
    gru_layer<1><<<grid, 512, 0, stream>>>(h1bf, w1bf, bi1, bh1, rows, Na, nullptr, out);
}

// Round 6
// 350.309 us; speedup vs baseline: 1.1973x; 1.1973x over previous
//
#include <hip/hip_runtime.h>
#include <hip/hip_bf16.h>
#include <cstdint>
#include <cstddef>

// Problem dims (fixed)
#define BB 16
#define LL 2048
#define MM (BB * LL)   // 32768 rows
#define KK 1024        // inner dim
#define HH 1024        // hidden per gate

typedef __attribute__((ext_vector_type(8))) short bf16x8;
typedef __attribute__((ext_vector_type(4))) float f32x4;

// ---------- fp32 -> bf16 (RNE) ----------
__device__ __forceinline__ unsigned short f2bf(float f) {
    unsigned u = __builtin_bit_cast(unsigned, f);
    u += 0x7fffu + ((u >> 16) & 1u);
    return (unsigned short)(u >> 16);
}

__global__ void cvt_f32_to_bf16(const float* __restrict__ in,
                                unsigned short* __restrict__ out, int n8) {
    int i = blockIdx.x * blockDim.x + threadIdx.x;
    if (i >= n8) return;
    const float4* p = reinterpret_cast<const float4*>(in) + (size_t)i * 2;
    float4 v0 = p[0];
    float4 v1 = p[1];
    union { unsigned short us[8]; uint4 v; } o;
    o.us[0] = f2bf(v0.x); o.us[1] = f2bf(v0.y);
    o.us[2] = f2bf(v0.z); o.us[3] = f2bf(v0.w);
    o.us[4] = f2bf(v1.x); o.us[5] = f2bf(v1.y);
    o.us[6] = f2bf(v1.z); o.us[7] = f2bf(v1.w);
    reinterpret_cast<uint4*>(out)[i] = o.v;
}

// ---------- mask scan ----------
__global__ __launch_bounds__(1024) void scan_mask(const int* __restrict__ mask,
                                                  int* __restrict__ rows,
                                                  int* __restrict__ Na) {
    __shared__ int psum[1024];
    const int t = threadIdx.x;
    const int base = t * 32;
    int m[32];
    int cnt = 0;
#pragma unroll
    for (int i = 0; i < 32; ++i) { m[i] = mask[base + i]; cnt += (m[i] != 0); }
    psum[t] = cnt;
    __syncthreads();
    for (int off = 1; off < 1024; off <<= 1) {
        int v = (t >= off) ? psum[t - off] : 0;
        __syncthreads();
        psum[t] += v;
        __syncthreads();
    }
    int offset = psum[t] - cnt;
#pragma unroll
    for (int i = 0; i < 32; ++i) {
        if (m[i]) rows[offset++] = base + i;
    }
    if (t == 1023) *Na = psum[1023];
}

// ---------- gather active rows of x, f32 -> bf16 ----------
__global__ __launch_bounds__(256) void gather_cvt(const float* __restrict__ x,
                                                  const int* __restrict__ rows,
                                                  const int* __restrict__ Na,
                                                  unsigned short* __restrict__ xbf) {
    const int j = blockIdx.x;
    if (j >= *Na) return;
    const int r = rows[j];
    const float4 v = reinterpret_cast<const float4*>(x + (size_t)r * KK)[threadIdx.x];
    ushort4 o;
    o.x = f2bf(v.x); o.y = f2bf(v.y); o.z = f2bf(v.z); o.w = f2bf(v.w);
    reinterpret_cast<ushort4*>(xbf + (size_t)j * KK)[threadIdx.x] = o;
}

// ---------- exact zeros for masked-out output rows ----------
__global__ __launch_bounds__(256) void zero_masked(const int* __restrict__ mask,
                                                   float* __restrict__ out) {
    const int m = blockIdx.x;
    if (mask[m] != 0) return;
    const int bb = m >> 11;
    const int ll = m & 2047;
    float4 z = {0.f, 0.f, 0.f, 0.f};
    reinterpret_cast<float4*>(out + ((size_t)ll * BB + bb) * HH)[threadIdx.x] = z;
}

// ---------- async global->LDS, 16B per lane ----------
__device__ __forceinline__ void gload16(const unsigned short* g, unsigned short* l) {
    __builtin_amdgcn_global_load_lds(
        (const __attribute__((address_space(1))) unsigned int*)g,
        (__attribute__((address_space(3))) unsigned int*)l,
        16, 0, 0);
}

#define WAITVM0 asm volatile("s_waitcnt vmcnt(0)" ::: "memory")
#define SB      __builtin_amdgcn_sched_barrier(0)
#define BAR     __builtin_amdgcn_s_barrier()

// ---------- fused GEMM + GRU gating, 2-phase double-buffered (T3-minimum) ----------
// BM=128, BN=64 x 3 gates, BK=32, 256 threads (4 waves, 2M x 2N).
// Buffer layout (shorts): A0[0,2048) A1[2048,4096) B0[4096..) B1 B2, 10240/buf.
// Swizzle: (row,k) stored at row*32 + ((k&7) | (((k>>3) ^ (row&3))<<3));
// staged via linear gload dest + inverse-swizzled global source (rule #21).
// Loop: STAGE(kt+1, buf^1) -> ds_read buf -> MFMA -> vmcnt(0) -> barrier.
// The drain now sits AFTER the compute phase, so load latency hides under MFMA.
template <int MODE>
__global__ __launch_bounds__(256, 2) void gru_layer(
    const unsigned short* __restrict__ A,
    const unsigned short* __restrict__ W,
    const float* __restrict__ b_ih,
    const float* __restrict__ b_hh,
    const int* __restrict__ rows,
    const int* __restrict__ Na_p,
    unsigned short* __restrict__ out_bf,
    float* __restrict__ out_f) {
    __shared__ unsigned short lds[2][10240];  // 40960 B

    const int Na = *Na_p;
    const int m0 = blockIdx.x * 128;
    if (m0 >= Na) return;
    const int n0 = blockIdx.y * 64;

    const int tid  = threadIdx.x;
    const int lane = tid & 63;
    const int wid  = tid >> 6;
    const int wr   = wid >> 1;  // 0..1
    const int wc   = wid & 1;   // 0..1

    // --- staging: thread t -> unit-linear slot t*16B = (row t/4, slot t&3) ---
    const int trow = tid >> 2;                          // 0..63 within unit
    const int tcol = ((tid & 3) ^ (trow & 3)) * 8;      // inverse-swizzled k (shorts)
    int r0 = m0 + trow;        if (r0 >= Na) r0 = Na - 1;
    int r1 = m0 + 64 + trow;   if (r1 >= Na) r1 = Na - 1;
    const unsigned short* a0 = A + (size_t)r0 * KK + tcol;
    const unsigned short* a1 = A + (size_t)r1 * KK + tcol;
    const unsigned short* b0 = W + (size_t)(0 * HH + n0 + trow) * KK + tcol;
    const unsigned short* b1 = W + (size_t)(1 * HH + n0 + trow) * KK + tcol;
    const unsigned short* b2 = W + (size_t)(2 * HH + n0 + trow) * KK + tcol;

#define STAGE(kt, c) do {                                        \
        const int _o = (kt) * 32;                                \
        unsigned short* _L = &lds[(c)][wid * 512];               \
        gload16(a0 + _o, _L + 0 * 2048);                         \
        gload16(a1 + _o, _L + 1 * 2048);                         \
        gload16(b0 + _o, _L + 2 * 2048);                         \
        gload16(b1 + _o, _L + 3 * 2048);                         \
        gload16(b2 + _o, _L + 4 * 2048);                         \
    } while (0)

    // --- read offsets (swizzled): lane l reads row(..+l15), kslot (l>>4)^(row&3) ---
    const int l15 = lane & 15;
    const int akp = (((lane >> 4) ^ (lane & 3)) & 3) << 3;   // shorts
    int aoff[4], boff[2];
#pragma unroll
    for (int mf = 0; mf < 4; ++mf)
        aoff[mf] = (wr * 64 + mf * 16 + l15) * 32 + akp;
#pragma unroll
    for (int nf = 0; nf < 2; ++nf)
        boff[nf] = 4096 + (wc * 32 + nf * 16 + l15) * 32 + akp;

    f32x4 accr[4][2] = {};
    f32x4 accz[4][2] = {};
    f32x4 accn[4][2] = {};

#define COMPUTE(Lp) do {                                                          \
        bf16x8 af[4];                                                             \
        _Pragma("unroll") for (int mf = 0; mf < 4; ++mf)                          \
            af[mf] = *reinterpret_cast<const bf16x8*>(&(Lp)[aoff[mf]]);           \
        _Pragma("unroll") for (int nf = 0; nf < 2; ++nf) {                        \
            bf16x8 br  = *reinterpret_cast<const bf16x8*>(&(Lp)[boff[nf]]);       \
            bf16x8 bz  = *reinterpret_cast<const bf16x8*>(&(Lp)[boff[nf] + 2048]);\
            bf16x8 bnn = *reinterpret_cast<const bf16x8*>(&(Lp)[boff[nf] + 4096]);\
            __builtin_amdgcn_s_setprio(1);                                        \
            _Pragma("unroll") for (int mf = 0; mf < 4; ++mf) {                    \
                accr[mf][nf] = __builtin_amdgcn_mfma_f32_16x16x32_bf16(           \
                    af[mf], br,  accr[mf][nf], 0, 0, 0);                          \
                accz[mf][nf] = __builtin_amdgcn_mfma_f32_16x16x32_bf16(           \
                    af[mf], bz,  accz[mf][nf], 0, 0, 0);                          \
                accn[mf][nf] = __builtin_amdgcn_mfma_f32_16x16x32_bf16(           \
                    af[mf], bnn, accn[mf][nf], 0, 0, 0);                          \
            }                                                                     \
            __builtin_amdgcn_s_setprio(0);                                        \
        }                                                                         \
    } while (0)

    // prologue: stage tile 0, drain, barrier
    STAGE(0, 0);
    WAITVM0; BAR; SB;

    int cur = 0;
#pragma unroll 1
    for (int kt = 0; kt < 31; ++kt) {
        STAGE(kt + 1, cur ^ 1);          // issue next-tile loads FIRST
        const unsigned short* L = &lds[cur][0];
        COMPUTE(L);                       // ds_read + MFMA hide the load latency
        WAITVM0; BAR; SB;                 // drain after compute, once per tile
        cur ^= 1;
    }
    {   // peeled last tile: no staging
        const unsigned short* L = &lds[cur][0];
        COMPUTE(L);
    }

    // --- epilogue: gating; C/D layout col = lane&15, row = (lane>>4)*4 + j ---
#pragma unroll
    for (int nf = 0; nf < 2; ++nf) {
        const int col = n0 + wc * 32 + nf * 16 + l15;
        const float br_b = b_ih[col] + b_hh[col];
        const float bz_b = b_ih[HH + col] + b_hh[HH + col];
        const float bn_i = b_ih[2 * HH + col];
        const float bn_h = b_hh[2 * HH + col];
#pragma unroll
        for (int mf = 0; mf < 4; ++mf) {
#pragma unroll
            for (int j = 0; j < 4; ++j) {
                const int row = m0 + wr * 64 + mf * 16 + (lane >> 4) * 4 + j;
                if (row >= Na) continue;
                const float r = 1.f / (1.f + __expf(-(accr[mf][nf][j] + br_b)));
                const float z = 1.f / (1.f + __expf(-(accz[mf][nf][j] + bz_b)));
                const float n = tanhf(accn[mf][nf][j] + bn_i + r * bn_h);
                const float h = (1.f - z) * n;
                if (MODE == 0) {
                    out_bf[(size_t)row * HH + col] = f2bf(h);
                } else {
                    const int orig = rows[row];
                    const int bb = orig >> 11;
                    const int ll = orig & 2047;
                    out_f[((size_t)ll * BB + bb) * HH + col] = h;
                }
            }
        }
    }
#undef STAGE
#undef COMPUTE
}

extern "C" void kernel_launch(void* const* d_in, const int* in_sizes, int n_in,
                              void* d_out, int out_size, void* d_ws, size_t ws_size,
                              hipStream_t stream) {
    const float* x   = (const float*)d_in[0];
    const int*   msk = (const int*)d_in[1];
    const float* W0  = (const float*)d_in[2];
    const float* bi0 = (const float*)d_in[4];
    const float* bh0 = (const float*)d_in[5];
    const float* W1  = (const float*)d_in[6];
    const float* bi1 = (const float*)d_in[8];
    const float* bh1 = (const float*)d_in[9];
    float* out = (float*)d_out;

    char* ws = (char*)d_ws;
    unsigned short* xbf  = (unsigned short*)ws;                  // 67,108,864 B (worst case)
    unsigned short* h1bf = (unsigned short*)(ws + 67108864);     // 67,108,864 B (worst case)
    unsigned short* w0bf = (unsigned short*)(ws + 134217728);    //  6,291,456 B
    unsigned short* w1bf = (unsigned short*)(ws + 140509184);    //  6,291,456 B
    int* rows = (int*)(ws + 146800640);                          //    131,072 B
    int* Na   = (int*)(ws + 146931712);                          //          4 B

    scan_mask<<<1, 1024, 0, stream>>>(msk, rows, Na);

    cvt_f32_to_bf16<<<1536, 256, 0, stream>>>(W0, w0bf, 3 * HH * KK / 8);
    cvt_f32_to_bf16<<<1536, 256, 0, stream>>>(W1, w1bf, 3 * HH * KK / 8);

    zero_masked<<<MM, 256, 0, stream>>>(msk, out);
    gather_cvt<<<MM, 256, 0, stream>>>(x, rows, Na, xbf);

    dim3 grid(MM / 128, HH / 64);  // (256, 16) worst case; blocks past Na exit
    gru_layer<0><<<grid, 256, 0, stream>>>(xbf, w0bf, bi0, bh0, rows, Na, h1bf, nullptr);
    gru_layer<1><<<grid, 256, 0, stream>>>(h1bf, w1bf, bi1, bh1, rows, Na, nullptr, out);
}